// Round 7
// baseline (135.203 us; speedup 1.0000x reference)
//
#include <hip/hip_runtime.h>
#include <math.h>

#define N 256
#define NN (N * N)      // 65536
#define NNN (N * N * N) // 16777216

__device__ inline float4 f4max(float4 a, float4 b) {
  return make_float4(fmaxf(a.x, b.x), fmaxf(a.y, b.y), fmaxf(a.z, b.z), fmaxf(a.w, b.w));
}
__device__ inline float4 f4add(float4 a, float4 b) {
  return make_float4(a.x + b.x, a.y + b.y, a.z + b.z, a.w + b.w);
}

// ===== reduce_bc: contiguous c-plane halves =====
// block = (b, c, h-half): reads x[b, c, hh*128:(hh+1)*128, :] (128 KiB contiguous)
//   zB{hh}[b][c][w] = max/mean over its 128 h   (partials merged in conv)
//   zCT[b][c][h]    = max/mean over w           (complete rows, transposed layout)
__global__ __launch_bounds__(256) void reduce_bc_kernel(
    const float* __restrict__ x,
    float* __restrict__ zB0max, float* __restrict__ zB0mean,
    float* __restrict__ zB1max, float* __restrict__ zB1mean,
    float* __restrict__ zCTmax, float* __restrict__ zCTmean) {
  __shared__ float pms[128][9][2];  // per local-row 8 w-partials (pad 9) x (m,s)
  __shared__ float gm[4][N];
  __shared__ float gs[4][N];
  const int lane = threadIdx.x & 63;
  const int g = threadIdx.x >> 6;
  const int hh = blockIdx.x & 1;
  const int bc = blockIdx.x >> 1;   // b*N + c
  const int b = bc >> 8, c = bc & 255;
  const float* p = x + (size_t)b * NNN + (size_t)c * NN +
                   (size_t)(hh * 128 + g * 32) * N + (lane << 2);
  float4 m4 = make_float4(-INFINITY, -INFINITY, -INFINITY, -INFINITY);
  float4 s4 = make_float4(0.f, 0.f, 0.f, 0.f);
#pragma unroll 4
  for (int i = 0; i < 32; ++i) {
    float4 v = *(const float4*)(p + (size_t)i * N);
    m4 = f4max(m4, v);
    s4 = f4add(s4, v);
    float m = fmaxf(fmaxf(v.x, v.y), fmaxf(v.z, v.w));
    float s = (v.x + v.y) + (v.z + v.w);
    m = fmaxf(m, __shfl_xor(m, 1));
    s += __shfl_xor(s, 1);
    m = fmaxf(m, __shfl_xor(m, 2));
    s += __shfl_xor(s, 2);
    m = fmaxf(m, __shfl_xor(m, 4));
    s += __shfl_xor(s, 4);
    if ((lane & 7) == 0) {
      const int l = g * 32 + i;  // local row 0..127
      pms[l][lane >> 3][0] = m;
      pms[l][lane >> 3][1] = s;
    }
  }
  const int w4 = lane << 2;
  *(float4*)&gm[g][w4] = m4;
  *(float4*)&gs[g][w4] = s4;
  __syncthreads();
  const int t = threadIdx.x;
  {  // zB partial for this h-half
    float m = fmaxf(fmaxf(gm[0][t], gm[1][t]), fmaxf(gm[2][t], gm[3][t]));
    float s = (gs[0][t] + gs[1][t] + gs[2][t] + gs[3][t]) * (1.f / 256.f);
    float* zm = hh ? zB1max : zB0max;
    float* zs = hh ? zB1mean : zB0mean;
    zm[(size_t)bc * N + t] = m;
    zs[(size_t)bc * N + t] = s;
  }
  if (t < 128) {  // zCT complete rows
    float m = pms[t][0][0];
    float s = pms[t][0][1];
#pragma unroll
    for (int i = 1; i < 8; ++i) {
      m = fmaxf(m, pms[t][i][0]);
      s += pms[t][i][1];
    }
    zCTmax[(size_t)bc * N + hh * 128 + t] = m;
    zCTmean[(size_t)bc * N + hh * 128 + t] = s * (1.f / 256.f);
  }
}

// ===== reduce_a: c-reduction with 8KB contiguous bursts =====
// block = (b, h-tile of 8 rows, c-group of 16): wave g owns rows h0+g, h0+4+g.
// Per c: the block reads 8 adjacent rows (8KB contiguous) before the 256KB jump.
// Pure elementwise register accumulation; partials to partM/partS (in d_out).
// partM layout: [(b*256+h)][16 cgroups][256 w]
__global__ __launch_bounds__(256) void reduce_a_kernel(
    const float* __restrict__ x,
    float* __restrict__ partM, float* __restrict__ partS) {
  const int lane = threadIdx.x & 63;
  const int g = threadIdx.x >> 6;
  const int a = blockIdx.x;        // B * 32 * 16
  const int b = a >> 9;
  const int ht = (a >> 4) & 31;
  const int cg = a & 15;
  const int h0 = ht << 3;
  const int c0 = cg << 4;
  const int w4 = lane << 2;
  const float* p0 = x + (size_t)b * NNN + (size_t)c0 * NN + (size_t)(h0 + g) * N + w4;
  const float* p1 = p0 + (size_t)4 * N;
  float4 m0 = make_float4(-INFINITY, -INFINITY, -INFINITY, -INFINITY);
  float4 s0 = make_float4(0.f, 0.f, 0.f, 0.f);
  float4 m1 = m0;
  float4 s1 = s0;
#pragma unroll 4
  for (int cc = 0; cc < 16; ++cc) {
    float4 v0 = *(const float4*)(p0 + (size_t)cc * NN);
    float4 v1 = *(const float4*)(p1 + (size_t)cc * NN);
    m0 = f4max(m0, v0);
    s0 = f4add(s0, v0);
    m1 = f4max(m1, v1);
    s1 = f4add(s1, v1);
  }
  const size_t o0 = (((size_t)(b << 8) + h0 + g) * 16 + cg) * N + w4;
  const size_t o1 = (((size_t)(b << 8) + h0 + 4 + g) * 16 + cg) * N + w4;
  *(float4*)(partM + o0) = m0;
  *(float4*)(partS + o0) = s0;
  *(float4*)(partM + o1) = m1;
  *(float4*)(partS + o1) = s1;
}

// ===== fold the 16 c-group partials into zA =====
__global__ __launch_bounds__(256) void fold_a_kernel(
    const float* __restrict__ partM, const float* __restrict__ partS,
    float* __restrict__ zAmax, float* __restrict__ zAmean) {
  const int bh = blockIdx.x;
  const int t = threadIdx.x;
  const float* pm = partM + (size_t)bh * 16 * N + t;
  const float* ps = partS + (size_t)bh * 16 * N + t;
  float m = pm[0];
  float s = ps[0];
#pragma unroll
  for (int g2 = 1; g2 < 16; ++g2) {
    m = fmaxf(m, pm[g2 * N]);
    s += ps[g2 * N];
  }
  zAmax[(size_t)bh * N + t] = m;
  zAmean[(size_t)bh * N + t] = s * (1.f / 256.f);
}

// -------- fused 7x7 conv (2ch->1) + BN + sigmoid for ALL THREE gates --------
// branch 0 (hw): zA single,            in [b][h][w], out Ghw[b][h][w]
// branch 1 (hc): zB dual-half merge,   in [b][c][w], out Ghc[b][c][w]
// branch 2 (wc): zCT TRANSPOSED [b][c][h]; block=(b,c), thread=h, out Gwc[b][h][c]
__global__ __launch_bounds__(256) void conv_gate3_kernel(
    const float* __restrict__ zAmax, const float* __restrict__ zAmean,
    const float* __restrict__ zB0max, const float* __restrict__ zB0mean,
    const float* __restrict__ zB1max, const float* __restrict__ zB1mean,
    const float* __restrict__ zCTmax, const float* __restrict__ zCTmean,
    const float* __restrict__ w_hw, const float* __restrict__ g_hw,
    const float* __restrict__ b_hw, const float* __restrict__ m_hw,
    const float* __restrict__ v_hw,
    const float* __restrict__ w_hc, const float* __restrict__ g_hc,
    const float* __restrict__ b_hc, const float* __restrict__ m_hc,
    const float* __restrict__ v_hc,
    const float* __restrict__ w_wc, const float* __restrict__ g_wc,
    const float* __restrict__ b_wc, const float* __restrict__ m_wc,
    const float* __restrict__ v_wc,
    float* __restrict__ Ghw, float* __restrict__ Ghc, float* __restrict__ Gwc,
    int BN) {
  const int branch = blockIdx.x / BN;
  const int bp = blockIdx.x - branch * BN;  // b*N + (p or c)
  const int b = bp >> 8;
  const size_t boff = (size_t)b * NN;

  if (branch == 2) {
    const int c = bp & 255;
    const int h = threadIdx.x;
    const float* zm = zCTmax + boff;
    const float* za = zCTmean + boff;
    float y = 0.f;
#pragma unroll
    for (int dc = 0; dc < 7; ++dc) {
      const int cc = c + dc - 3;
      if ((unsigned)cc < N) {
#pragma unroll
        for (int dh = 0; dh < 7; ++dh) {
          const int hh = h + dh - 3;
          if ((unsigned)hh < N) {
            const int idx = cc * N + hh;
            y += zm[idx] * w_wc[dh * 7 + dc] + za[idx] * w_wc[49 + dh * 7 + dc];
          }
        }
      }
    }
    const float scale = g_wc[0] * rsqrtf(v_wc[0] + 1e-5f);
    const float yb = (y - m_wc[0]) * scale + b_wc[0];
    Gwc[boff + (size_t)h * N + c] = 1.f / (1.f + __expf(-yb));
    return;
  }

  const int p = bp & 255;
  const int q = threadIdx.x;
  const float *zm0, *zm1, *za0, *za1;
  const float *wt, *gg, *bb, *mm, *vv;
  float* gate;
  bool dual;
  if (branch == 0) {
    zm0 = zAmax; zm1 = zAmax; za0 = zAmean; za1 = zAmean; dual = false;
    wt = w_hw; gg = g_hw; bb = b_hw; mm = m_hw; vv = v_hw; gate = Ghw;
  } else {
    zm0 = zB0max; zm1 = zB1max; za0 = zB0mean; za1 = zB1mean; dual = true;
    wt = w_hc; gg = g_hc; bb = b_hc; mm = m_hc; vv = v_hc; gate = Ghc;
  }
  zm0 += boff; zm1 += boff; za0 += boff; za1 += boff;
  float y = 0.f;
#pragma unroll
  for (int dh = 0; dh < 7; ++dh) {
    const int pp = p + dh - 3;
    if ((unsigned)pp < N) {
#pragma unroll
      for (int dw = 0; dw < 7; ++dw) {
        const int qq = q + dw - 3;
        if ((unsigned)qq < N) {
          const int idx = pp * N + qq;
          const float zm = dual ? fmaxf(zm0[idx], zm1[idx]) : zm0[idx];
          const float za = dual ? (za0[idx] + za1[idx]) : za0[idx];
          y += zm * wt[dh * 7 + dw] + za * wt[49 + dh * 7 + dw];
        }
      }
    }
  }
  const float scale = gg[0] * rsqrtf(vv[0] + 1e-5f);
  const float yb = (y - mm[0]) * scale + bb[0];
  gate[boff + (size_t)p * N + q] = 1.f / (1.f + __expf(-yb));
}

// -------- final combine --------
// out[b,i,j,k] = ( x[b,i,j,k]*(Ghw[b,j,k]+Ghc[b,i,k]) + x[b,k,i,j]*Gwc[b,i,k] ) / 3
__global__ __launch_bounds__(256) void combine_kernel(
    const float* __restrict__ x, const float* __restrict__ Ghw,
    const float* __restrict__ Ghc, const float* __restrict__ Gwc,
    float* __restrict__ out) {
  __shared__ float t[32][33]; // t[kk][jj] = x[b, k0+kk, i, j0+jj]
  const int blk = blockIdx.x;
  const int kt = blk & 7, jt = (blk >> 3) & 7, i = (blk >> 6) & 255, b = blk >> 14;
  const int k0 = kt << 5, j0 = jt << 5;
  const int rowi = threadIdx.x >> 3;        // 0..31
  const int col4 = (threadIdx.x & 7) << 2;  // 0,4,...,28
  {
    float4 v = *(const float4*)(x + ((size_t)b << 24) + ((size_t)(k0 + rowi) << 16) +
                                ((size_t)i << 8) + j0 + col4);
    t[rowi][col4 + 0] = v.x;
    t[rowi][col4 + 1] = v.y;
    t[rowi][col4 + 2] = v.z;
    t[rowi][col4 + 3] = v.w;
  }
  __syncthreads();
  const int jj = rowi;        // output row within tile
  const int k = k0 + col4;    // output col quad
  const size_t gik = (((size_t)(b << 8) + i) << 8) + k; // (b*N+i)*N + k
  const float4 ghc = *(const float4*)(Ghc + gik);
  const float4 gwc = *(const float4*)(Gwc + gik);
  const size_t base = ((size_t)b << 24) + ((size_t)i << 16) + ((size_t)(j0 + jj) << 8) + k;
  const float4 xv = *(const float4*)(x + base);
  const float4 ghw = *(const float4*)(Ghw + ((size_t)b << 16) + ((size_t)(j0 + jj) << 8) + k);
  const float third = 1.f / 3.f;
  float4 r;
  r.x = (xv.x * (ghw.x + ghc.x) + t[col4 + 0][jj] * gwc.x) * third;
  r.y = (xv.y * (ghw.y + ghc.y) + t[col4 + 1][jj] * gwc.y) * third;
  r.z = (xv.z * (ghw.z + ghc.z) + t[col4 + 2][jj] * gwc.z) * third;
  r.w = (xv.w * (ghw.w + ghc.w) + t[col4 + 3][jj] * gwc.w) * third;
  *(float4*)(out + base) = r;
}

extern "C" void kernel_launch(void* const* d_in, const int* in_sizes, int n_in,
                              void* d_out, int out_size, void* d_ws, size_t ws_size,
                              hipStream_t stream) {
  const float* x    = (const float*)d_in[0];
  const float* w_hw = (const float*)d_in[1];
  const float* g_hw = (const float*)d_in[2];
  const float* b_hw = (const float*)d_in[3];
  const float* m_hw = (const float*)d_in[4];
  const float* v_hw = (const float*)d_in[5];
  const float* w_hc = (const float*)d_in[6];
  const float* g_hc = (const float*)d_in[7];
  const float* b_hc = (const float*)d_in[8];
  const float* m_hc = (const float*)d_in[9];
  const float* v_hc = (const float*)d_in[10];
  const float* w_wc = (const float*)d_in[11];
  const float* g_wc = (const float*)d_in[12];
  const float* b_wc = (const float*)d_in[13];
  const float* m_wc = (const float*)d_in[14];
  const float* v_wc = (const float*)d_in[15];

  const int B = in_sizes[0] / NNN; // 2
  const int BN = B * N;
  const size_t plane = (size_t)B * NN;
  float* ws = (float*)d_ws;
  float* zB0max  = ws + 0 * plane;
  float* zB0mean = ws + 1 * plane;
  float* zB1max  = ws + 2 * plane;
  float* zB1mean = ws + 3 * plane;
  float* zCTmax  = ws + 4 * plane;
  float* zCTmean = ws + 5 * plane;
  float* zAmax   = ws + 6 * plane;
  float* zAmean  = ws + 7 * plane;
  float* GhwP    = ws + 8 * plane;
  float* GhcP    = ws + 9 * plane;
  float* GwcP    = ws + 10 * plane;

  // zA c-group partials parked in d_out (consumed before combine overwrites)
  float* partM = (float*)d_out;
  float* partS = partM + plane * 16;

  reduce_bc_kernel<<<2 * BN, 256, 0, stream>>>(
      x, zB0max, zB0mean, zB1max, zB1mean, zCTmax, zCTmean);
  reduce_a_kernel<<<B * 32 * 16, 256, 0, stream>>>(x, partM, partS);
  fold_a_kernel<<<BN, 256, 0, stream>>>(partM, partS, zAmax, zAmean);

  conv_gate3_kernel<<<3 * BN, 256, 0, stream>>>(
      zAmax, zAmean, zB0max, zB0mean, zB1max, zB1mean, zCTmax, zCTmean,
      w_hw, g_hw, b_hw, m_hw, v_hw,
      w_hc, g_hc, b_hc, m_hc, v_hc,
      w_wc, g_wc, b_wc, m_wc, v_wc,
      GhwP, GhcP, GwcP, BN);

  combine_kernel<<<B * N * 64, 256, 0, stream>>>(x, GhwP, GhcP, GwcP, (float*)d_out);
}